// Round 5
// baseline (15088.028 us; speedup 1.0000x reference)
//
#include <hip/hip_runtime.h>
#include <math.h>
#include <float.h>
#include <limits.h>

#define BB 64        // batch (== wavefront size)
#define HID 768
#define VOCAB 30000
#define NG 3072      // 4*HID
#define TSTEPS 32
#define NBG 469      // ceil(30000/64) col-groups for klog
#define KSPLIT 8     // kg1 K-split (gates)

// ---------------------------------------------------------------------------
// Closed head stage 1: hid[b][r] = relu(feat[b] . c1W[r] + c1b[r]).
// ---------------------------------------------------------------------------
__global__ __launch_bounds__(256) void kc1(
    const float* __restrict__ feat, const float* __restrict__ c1W,
    const float* __restrict__ c1b, float* __restrict__ hid_ws)
{
    const int q = blockIdx.x, b = blockIdx.y;
    const int wave = threadIdx.x >> 6, lane = threadIdx.x & 63;
    float4 fr[3];
    const float4* frow = (const float4*)(feat + (size_t)b * HID);
    #pragma unroll
    for (int j = 0; j < 3; j++) fr[j] = frow[lane + 64 * j];

    #pragma unroll 2
    for (int rr = 0; rr < 32; rr++) {
        const int r = q * 128 + wave * 32 + rr;
        const float4* w = (const float4*)(c1W + (size_t)r * HID);
        float s = 0.f;
        #pragma unroll
        for (int j = 0; j < 3; j++) {
            float4 wv = w[lane + 64 * j];
            s += fr[j].x * wv.x + fr[j].y * wv.y + fr[j].z * wv.z + fr[j].w * wv.w;
        }
        #pragma unroll
        for (int o = 32; o; o >>= 1) s += __shfl_xor(s, o, 64);
        if (lane == 0) hid_ws[b * 512 + r] = fmaxf(s + c1b[r], 0.f);
    }
}

// Closed head stage 2.
__global__ __launch_bounds__(256) void kc2(
    const float* __restrict__ hid_ws, const float* __restrict__ c2W,
    const float* __restrict__ c2b, float* __restrict__ out)
{
    const int b = blockIdx.x, tid = threadIdx.x;
    __shared__ float red[2][256];
    float s0 = 0.f, s1 = 0.f;
    for (int r = tid; r < 512; r += 256) {
        float hv = hid_ws[b * 512 + r];
        s0 += hv * c2W[r];
        s1 += hv * c2W[512 + r];
    }
    red[0][tid] = s0; red[1][tid] = s1;
    __syncthreads();
    for (int st = 128; st; st >>= 1) {
        if (tid < st) { red[0][tid] += red[0][tid + st]; red[1][tid] += red[1][tid + st]; }
        __syncthreads();
    }
    if (tid == 0) {
        out[b * 2 + 0] = red[0][0] + c2b[0];
        out[b * 2 + 1] = red[1][0] + c2b[1];
    }
}

// ---------------------------------------------------------------------------
// Prep: hT[k][b] = feat[b][k]  (transposed h0 for klog).
// ---------------------------------------------------------------------------
__global__ __launch_bounds__(256) void kprep(
    const float* __restrict__ feat, float* __restrict__ hT)
{
    int idx = blockIdx.x * 256 + threadIdx.x;   // < 768*64
    int k = idx >> 6, b = idx & 63;
    hT[idx] = feat[b * HID + k];
}

// ---------------------------------------------------------------------------
// Gates GEMM partial: grid (48, 8). nc = 64-col chunk of 3072; ks<4:
// x = emb[tok] @ W_ih K-quarter; ks>=4: h @ W_hh K-quarter. K=192/block.
// ---------------------------------------------------------------------------
__global__ __launch_bounds__(256) void kg1(
    int step, const int* __restrict__ tok_ws, const float* __restrict__ emb,
    const float* __restrict__ W_ih, const float* __restrict__ W_hh,
    const float* __restrict__ h_in, float* __restrict__ gpart)
{
    const int tid = threadIdx.x;
    const int nc = blockIdx.x;   // 0..47
    const int ks = blockIdx.y;   // 0..7
    __shared__ int tok_lds[BB];
    __shared__ float as[32][68];
    __shared__ float wsl[32][68];

    if (ks < 4 && tid < BB)
        tok_lds[tid] = (step == 0) ? 0 : tok_ws[tid];
    __syncthreads();

    const int ty = tid >> 4, tx = tid & 15;
    float acc[4][4] = {};

    for (int k0 = 0; k0 < 192; k0 += 32) {
        for (int i = tid; i < 512; i += 256) {   // A: 64 rows x 32 k
            int r = i >> 3, kq = i & 7;
            const float* base = (ks < 4)
                ? (emb + (size_t)tok_lds[r] * HID + ks * 192)
                : (h_in + (size_t)r * HID + (ks - 4) * 192);
            float4 v = *(const float4*)(base + k0 + kq * 4);
            as[kq*4+0][r] = v.x; as[kq*4+1][r] = v.y;
            as[kq*4+2][r] = v.z; as[kq*4+3][r] = v.w;
        }
        for (int i = tid; i < 512; i += 256) {   // W: 64 cols x 32 k
            int c = i >> 3, kq = i & 7;
            int gcol = nc * 64 + c;
            const float* wb = (ks < 4)
                ? (W_ih + (size_t)gcol * HID + ks * 192)
                : (W_hh + (size_t)gcol * HID + (ks - 4) * 192);
            float4 v = *(const float4*)(wb + k0 + kq * 4);
            wsl[kq*4+0][c] = v.x; wsl[kq*4+1][c] = v.y;
            wsl[kq*4+2][c] = v.z; wsl[kq*4+3][c] = v.w;
        }
        __syncthreads();
        #pragma unroll
        for (int kk = 0; kk < 32; kk++) {
            float4 av = *(const float4*)&as[kk][ty * 4];
            float4 wv = *(const float4*)&wsl[kk][tx * 4];
            acc[0][0] += av.x*wv.x; acc[0][1] += av.x*wv.y; acc[0][2] += av.x*wv.z; acc[0][3] += av.x*wv.w;
            acc[1][0] += av.y*wv.x; acc[1][1] += av.y*wv.y; acc[1][2] += av.y*wv.z; acc[1][3] += av.y*wv.w;
            acc[2][0] += av.z*wv.x; acc[2][1] += av.z*wv.y; acc[2][2] += av.z*wv.z; acc[2][3] += av.z*wv.w;
            acc[3][0] += av.w*wv.x; acc[3][1] += av.w*wv.y; acc[3][2] += av.w*wv.z; acc[3][3] += av.w*wv.w;
        }
        __syncthreads();
    }
    #pragma unroll
    for (int i = 0; i < 4; i++) {
        float4 v = make_float4(acc[i][0], acc[i][1], acc[i][2], acc[i][3]);
        *(float4*)(gpart + ((size_t)(ks * BB) + ty * 4 + i) * NG + nc * 64 + tx * 4) = v;
    }
}

// ---------------------------------------------------------------------------
// Cell: sum 8 K-partials (fixed order) + biases, LSTM update. Writes h both
// b-major (for kg1) and transposed hT[k][b] (for klog).
// ---------------------------------------------------------------------------
__global__ __launch_bounds__(256) void kc(
    int step, const float* __restrict__ gpart, const float* __restrict__ b_ih,
    const float* __restrict__ b_hh, float* __restrict__ cbuf,
    float* __restrict__ h_out, float* __restrict__ hT)
{
    int idx = blockIdx.x * 256 + threadIdx.x;   // < 64*768
    int b = idx / HID, j = idx % HID;
    float g4[4];
    #pragma unroll
    for (int g = 0; g < 4; g++) {
        int col = g * HID + j;
        float s = b_ih[col] + b_hh[col];
        #pragma unroll
        for (int ksd = 0; ksd < KSPLIT; ksd++)
            s += gpart[((size_t)ksd * BB + b) * NG + col];
        g4[g] = s;
    }
    float cprev = (step == 0) ? 0.f : cbuf[idx];
    float ig = 1.f / (1.f + expf(-g4[0]));
    float fg = 1.f / (1.f + expf(-g4[1]));
    float gg = tanhf(g4[2]);
    float og = 1.f / (1.f + expf(-g4[3]));
    float cn = fg * cprev + ig * gg;
    float hn = og * tanhf(cn);
    cbuf[idx] = cn;
    h_out[idx] = hn;
    hT[j * 64 + b] = hn;
}

// ---------------------------------------------------------------------------
// Logits GEMM + fused argmax — kg1 tile, straight-line deep pipeline.
//
// 469 blocks x 256 thr; block = 64 rows x 64 cols, K=768 = 24 chunks of 32.
// Double-buffered LDS (as/bs x2 = 34.8 KB), ONE barrier per chunk. Named
// prefetch register sets s0/s1 (no lambdas, no runtime-indexed arrays):
// loads for chunk c+2 are issued in the phase computing chunk c, and their
// LDS-write happens in the phase computing chunk c+1 — every load has a
// full >=1024-cycle compute phase to cover ~900-cycle HBM latency before
// its vmcnt wait. __launch_bounds__(256,4) caps VGPR at 128 so the whole
// 469-block grid (1876 waves) is co-resident (~2 blocks/CU of extra TLP).
// Inner loop identical to kg1 (conflict-free: A broadcast, B 2-way).
// Epilogue: bias + per-row 16-lane shuffle argmax (first-occurrence ties).
// ---------------------------------------------------------------------------
__global__ __launch_bounds__(256, 4) void klog(
    const float* __restrict__ hT, const float* __restrict__ outW,
    const float* __restrict__ outb, float* __restrict__ pval, int* __restrict__ pidx)
{
    __shared__ float as[2][32][68];
    __shared__ float bs[2][32][68];

    const int tid = threadIdx.x;
    const int cb  = blockIdx.x;
    const int c0  = cb * 64;
    const int ty  = tid >> 4, tx = tid & 15;

    // staging coordinates (fixed per thread)
    const int ak0 = tid >> 4;          // A row (k) 0..15 (and +16)
    const int ab4 = (tid & 15) * 4;    // A batch offset
    const int bc  = tid >> 3;          // B col 0..31 (and +32)
    const int bkq = tid & 7;           // B k-quarter

    const int bcol0 = c0 + bc;
    const int bcol1 = c0 + bc + 32;
    const float* bW0 = outW + (size_t)((bcol0 < VOCAB) ? bcol0 : VOCAB - 1) * HID + bkq * 4;
    const float* bW1 = outW + (size_t)((bcol1 < VOCAB) ? bcol1 : VOCAB - 1) * HID + bkq * 4;
    const float* hA0 = hT + (size_t)ak0 * 64 + ab4;          // + c*2048
    const float* hA1 = hT + (size_t)(ak0 + 16) * 64 + ab4;   // + c*2048

    float acc[4][4] = {};

    // ---- macros: straight-line staging (no lambdas) ----
#define KLOG_LD(c, A0, A1, B0, B1)                                   \
    {   const int _c = (c);                                          \
        A0 = *(const float4*)(hA0 + _c * 2048);                      \
        A1 = *(const float4*)(hA1 + _c * 2048);                      \
        B0 = *(const float4*)(bW0 + _c * 32);                        \
        B1 = *(const float4*)(bW1 + _c * 32);                        \
    }
#define KLOG_WR(buf, A0, A1, B0, B1)                                 \
    {   *(float4*)&as[buf][ak0][ab4]      = A0;                      \
        *(float4*)&as[buf][ak0 + 16][ab4] = A1;                      \
        bs[buf][bkq*4+0][bc] = B0.x; bs[buf][bkq*4+1][bc] = B0.y;    \
        bs[buf][bkq*4+2][bc] = B0.z; bs[buf][bkq*4+3][bc] = B0.w;    \
        bs[buf][bkq*4+0][bc+32] = B1.x; bs[buf][bkq*4+1][bc+32] = B1.y; \
        bs[buf][bkq*4+2][bc+32] = B1.z; bs[buf][bkq*4+3][bc+32] = B1.w; \
    }
#define KLOG_COMPUTE(buf)                                                            \
    _Pragma("unroll")                                                                \
    for (int kk = 0; kk < 32; kk++) {                                                \
        float4 av = *(const float4*)&as[buf][kk][ty * 4];                            \
        float4 wv = *(const float4*)&bs[buf][kk][tx * 4];                            \
        acc[0][0] = fmaf(av.x, wv.x, acc[0][0]); acc[0][1] = fmaf(av.x, wv.y, acc[0][1]); \
        acc[0][2] = fmaf(av.x, wv.z, acc[0][2]); acc[0][3] = fmaf(av.x, wv.w, acc[0][3]); \
        acc[1][0] = fmaf(av.y, wv.x, acc[1][0]); acc[1][1] = fmaf(av.y, wv.y, acc[1][1]); \
        acc[1][2] = fmaf(av.y, wv.z, acc[1][2]); acc[1][3] = fmaf(av.y, wv.w, acc[1][3]); \
        acc[2][0] = fmaf(av.z, wv.x, acc[2][0]); acc[2][1] = fmaf(av.z, wv.y, acc[2][1]); \
        acc[2][2] = fmaf(av.z, wv.z, acc[2][2]); acc[2][3] = fmaf(av.z, wv.w, acc[2][3]); \
        acc[3][0] = fmaf(av.w, wv.x, acc[3][0]); acc[3][1] = fmaf(av.w, wv.y, acc[3][1]); \
        acc[3][2] = fmaf(av.w, wv.z, acc[3][2]); acc[3][3] = fmaf(av.w, wv.w, acc[3][3]); \
    }

    // prefetch register sets (named; no runtime indexing)
    float4 s0a0, s0a1, s0b0, s0b1;
    float4 s1a0, s1a1, s1b0, s1b1;

    // ---- prologue: chunks 0 and 1 in flight; chunk 0 -> buf0 ----
    KLOG_LD(0, s0a0, s0a1, s0b0, s0b1);
    KLOG_LD(1, s1a0, s1a1, s1b0, s1b1);
    KLOG_WR(0, s0a0, s0a1, s0b0, s0b1);
    __syncthreads();

    for (int c = 0; c < 24; c += 2) {
        // ---- even phase: compute chunk c (buf0) ----
        KLOG_WR(1, s1a0, s1a1, s1b0, s1b1);        // chunk c+1 -> buf1 (loads 1 phase old)
        if (c + 2 < 24) KLOG_LD(c + 2, s0a0, s0a1, s0b0, s0b1);
        KLOG_COMPUTE(0);
        __syncthreads();

        // ---- odd phase: compute chunk c+1 (buf1) ----
        if (c + 2 < 24) KLOG_WR(0, s0a0, s0a1, s0b0, s0b1);   // chunk c+2 -> buf0
        if (c + 3 < 24) KLOG_LD(c + 3, s1a0, s1a1, s1b0, s1b1);
        KLOG_COMPUTE(1);
        __syncthreads();
    }
#undef KLOG_LD
#undef KLOG_WR
#undef KLOG_COMPUTE

    // ---- epilogue: bias + per-row argmax over the block's 64 cols ----
    float ob[4];
    #pragma unroll
    for (int j = 0; j < 4; j++) {
        int cix = c0 + tx * 4 + j;
        ob[j] = (cix < VOCAB) ? outb[cix] : 0.f;
    }
    #pragma unroll
    for (int i = 0; i < 4; i++) {
        const int row = ty * 4 + i;
        float bv = -FLT_MAX; int bi = INT_MAX;
        #pragma unroll
        for (int j = 0; j < 4; j++) {
            int cix = c0 + tx * 4 + j;
            if (cix < VOCAB) {
                float v = acc[i][j] + ob[j];
                if (v > bv) { bv = v; bi = cix; }   // j ascending -> first occurrence
            }
        }
        // reduce across the 16-lane tx-group (lanes ty*16 .. ty*16+15)
        #pragma unroll
        for (int off = 1; off < 16; off <<= 1) {
            float vv = __shfl_xor(bv, off, 64);
            int   ii = __shfl_xor(bi, off, 64);
            if (vv > bv || (vv == bv && ii < bi)) { bv = vv; bi = ii; }
        }
        if (tx == 0) {
            pval[(size_t)row * NBG + cb] = bv;
            pidx[(size_t)row * NBG + cb] = bi;
        }
    }
}

// ---------------------------------------------------------------------------
// Finalize token for batch row b.
// ---------------------------------------------------------------------------
__global__ __launch_bounds__(256) void kfin(
    int step, const float* __restrict__ pval, const int* __restrict__ pidx,
    int* __restrict__ tok_ws, float* __restrict__ gen)
{
    const int b = blockIdx.x, tid = threadIdx.x;
    __shared__ float sv[256];
    __shared__ int   si[256];
    float bv = -FLT_MAX; int bi = INT_MAX;
    for (int p = tid; p < NBG; p += 256) {
        float v = pval[(size_t)b * NBG + p]; int ix = pidx[(size_t)b * NBG + p];
        if (v > bv || (v == bv && ix < bi)) { bv = v; bi = ix; }
    }
    sv[tid] = bv; si[tid] = bi;
    __syncthreads();
    for (int st = 128; st; st >>= 1) {
        if (tid < st) {
            float v = sv[tid + st]; int ix = si[tid + st];
            if (v > sv[tid] || (v == sv[tid] && ix < si[tid])) { sv[tid] = v; si[tid] = ix; }
        }
        __syncthreads();
    }
    if (tid == 0) {
        tok_ws[b] = si[0];
        gen[b * TSTEPS + step] = (float)si[0];
    }
}

// ---------------------------------------------------------------------------
extern "C" void kernel_launch(void* const* d_in, const int* in_sizes, int n_in,
                              void* d_out, int out_size, void* d_ws, size_t ws_size,
                              hipStream_t stream)
{
    const float* feat = (const float*)d_in[0];
    const float* emb  = (const float*)d_in[1];
    const float* W_ih = (const float*)d_in[2];
    const float* W_hh = (const float*)d_in[3];
    const float* b_ih = (const float*)d_in[4];
    const float* b_hh = (const float*)d_in[5];
    const float* outW = (const float*)d_in[6];
    const float* outb = (const float*)d_in[7];
    const float* c1W  = (const float*)d_in[8];
    const float* c1b  = (const float*)d_in[9];
    const float* c2W  = (const float*)d_in[10];
    const float* c2b  = (const float*)d_in[11];
    (void)in_sizes; (void)n_in; (void)out_size; (void)ws_size;

    float* out = (float*)d_out;
    float* gen = out + BB * 2;                  // generated (64x32), as floats

    float* ws     = (float*)d_ws;
    float* hbuf   = ws;                               // 64*768  (b-major h)
    float* cbuf   = hbuf + BB * HID;                  // 64*768
    float* hT     = cbuf + BB * HID;                  // 768*64  (k-major h)
    float* gpart  = hT + HID * 64;                    // 8*64*3072
    float* pval   = gpart + (size_t)KSPLIT * BB * NG; // 64*469
    int*   pidx   = (int*)(pval + BB * NBG);          // 64*469
    int*   tok    = pidx + BB * NBG;                  // 64
    float* hid_ws = (float*)(tok + BB);               // 64*512

    kc1<<<dim3(4, BB), 256, 0, stream>>>(feat, c1W, c1b, hid_ws);
    kc2<<<BB, 256, 0, stream>>>(hid_ws, c2W, c2b, out);
    kprep<<<dim3(HID * 64 / 256), 256, 0, stream>>>(feat, hT);

    for (int t = 0; t < TSTEPS; t++) {
        const float* h_in = (t == 0) ? feat : hbuf;
        kg1<<<dim3(48, KSPLIT), 256, 0, stream>>>(t, tok, emb, W_ih, W_hh, h_in, gpart);
        kc<<<dim3(192), 256, 0, stream>>>(t, gpart, b_ih, b_hh, cbuf, hbuf, hT);
        klog<<<dim3(NBG), 256, 0, stream>>>(hT, outW, outb, pval, pidx);
        kfin<<<BB, 256, 0, stream>>>(t, pval, pidx, tok, gen);
    }
}

// Round 7
// 2890.101 us; speedup vs baseline: 5.2206x; 5.2206x over previous
//
#include <hip/hip_runtime.h>
#include <math.h>
#include <float.h>
#include <limits.h>

#define BB 64        // batch (== wavefront size)
#define HID 768
#define VOCAB 30000
#define NG 3072      // 4*HID
#define TSTEPS 32
#define NBL 235      // ceil(30000/128) col-groups for klog
#define KSPLIT 8     // kg1 K-split (gates)

// ---------------------------------------------------------------------------
// Closed head stage 1: hid[b][r] = relu(feat[b] . c1W[r] + c1b[r]).
// ---------------------------------------------------------------------------
__global__ __launch_bounds__(256) void kc1(
    const float* __restrict__ feat, const float* __restrict__ c1W,
    const float* __restrict__ c1b, float* __restrict__ hid_ws)
{
    const int q = blockIdx.x, b = blockIdx.y;
    const int wave = threadIdx.x >> 6, lane = threadIdx.x & 63;
    float4 fr[3];
    const float4* frow = (const float4*)(feat + (size_t)b * HID);
    #pragma unroll
    for (int j = 0; j < 3; j++) fr[j] = frow[lane + 64 * j];

    #pragma unroll 2
    for (int rr = 0; rr < 32; rr++) {
        const int r = q * 128 + wave * 32 + rr;
        const float4* w = (const float4*)(c1W + (size_t)r * HID);
        float s = 0.f;
        #pragma unroll
        for (int j = 0; j < 3; j++) {
            float4 wv = w[lane + 64 * j];
            s += fr[j].x * wv.x + fr[j].y * wv.y + fr[j].z * wv.z + fr[j].w * wv.w;
        }
        #pragma unroll
        for (int o = 32; o; o >>= 1) s += __shfl_xor(s, o, 64);
        if (lane == 0) hid_ws[b * 512 + r] = fmaxf(s + c1b[r], 0.f);
    }
}

// Closed head stage 2.
__global__ __launch_bounds__(256) void kc2(
    const float* __restrict__ hid_ws, const float* __restrict__ c2W,
    const float* __restrict__ c2b, float* __restrict__ out)
{
    const int b = blockIdx.x, tid = threadIdx.x;
    __shared__ float red[2][256];
    float s0 = 0.f, s1 = 0.f;
    for (int r = tid; r < 512; r += 256) {
        float hv = hid_ws[b * 512 + r];
        s0 += hv * c2W[r];
        s1 += hv * c2W[512 + r];
    }
    red[0][tid] = s0; red[1][tid] = s1;
    __syncthreads();
    for (int st = 128; st; st >>= 1) {
        if (tid < st) { red[0][tid] += red[0][tid + st]; red[1][tid] += red[1][tid + st]; }
        __syncthreads();
    }
    if (tid == 0) {
        out[b * 2 + 0] = red[0][0] + c2b[0];
        out[b * 2 + 1] = red[1][0] + c2b[1];
    }
}

// ---------------------------------------------------------------------------
// Prep: hT[k][b] = feat[b][k]  (transposed h0 for klog).
// ---------------------------------------------------------------------------
__global__ __launch_bounds__(256) void kprep(
    const float* __restrict__ feat, float* __restrict__ hT)
{
    int idx = blockIdx.x * 256 + threadIdx.x;   // < 768*64
    int k = idx >> 6, b = idx & 63;
    hT[idx] = feat[b * HID + k];
}

// ---------------------------------------------------------------------------
// Gates GEMM partial: grid (48, 8). nc = 64-col chunk of 3072; ks<4:
// x = emb[tok] @ W_ih K-quarter; ks>=4: h @ W_hh K-quarter. K=192/block.
// ---------------------------------------------------------------------------
__global__ __launch_bounds__(256) void kg1(
    int step, const int* __restrict__ tok_ws, const float* __restrict__ emb,
    const float* __restrict__ W_ih, const float* __restrict__ W_hh,
    const float* __restrict__ h_in, float* __restrict__ gpart)
{
    const int tid = threadIdx.x;
    const int nc = blockIdx.x;   // 0..47
    const int ks = blockIdx.y;   // 0..7
    __shared__ int tok_lds[BB];
    __shared__ float as[32][68];
    __shared__ float wsl[32][68];

    if (ks < 4 && tid < BB)
        tok_lds[tid] = (step == 0) ? 0 : tok_ws[tid];
    __syncthreads();

    const int ty = tid >> 4, tx = tid & 15;
    float acc[4][4] = {};

    for (int k0 = 0; k0 < 192; k0 += 32) {
        for (int i = tid; i < 512; i += 256) {   // A: 64 rows x 32 k
            int r = i >> 3, kq = i & 7;
            const float* base = (ks < 4)
                ? (emb + (size_t)tok_lds[r] * HID + ks * 192)
                : (h_in + (size_t)r * HID + (ks - 4) * 192);
            float4 v = *(const float4*)(base + k0 + kq * 4);
            as[kq*4+0][r] = v.x; as[kq*4+1][r] = v.y;
            as[kq*4+2][r] = v.z; as[kq*4+3][r] = v.w;
        }
        for (int i = tid; i < 512; i += 256) {   // W: 64 cols x 32 k
            int c = i >> 3, kq = i & 7;
            int gcol = nc * 64 + c;
            const float* wb = (ks < 4)
                ? (W_ih + (size_t)gcol * HID + ks * 192)
                : (W_hh + (size_t)gcol * HID + (ks - 4) * 192);
            float4 v = *(const float4*)(wb + k0 + kq * 4);
            wsl[kq*4+0][c] = v.x; wsl[kq*4+1][c] = v.y;
            wsl[kq*4+2][c] = v.z; wsl[kq*4+3][c] = v.w;
        }
        __syncthreads();
        #pragma unroll
        for (int kk = 0; kk < 32; kk++) {
            float4 av = *(const float4*)&as[kk][ty * 4];
            float4 wv = *(const float4*)&wsl[kk][tx * 4];
            acc[0][0] += av.x*wv.x; acc[0][1] += av.x*wv.y; acc[0][2] += av.x*wv.z; acc[0][3] += av.x*wv.w;
            acc[1][0] += av.y*wv.x; acc[1][1] += av.y*wv.y; acc[1][2] += av.y*wv.z; acc[1][3] += av.y*wv.w;
            acc[2][0] += av.z*wv.x; acc[2][1] += av.z*wv.y; acc[2][2] += av.z*wv.z; acc[2][3] += av.z*wv.w;
            acc[3][0] += av.w*wv.x; acc[3][1] += av.w*wv.y; acc[3][2] += av.w*wv.z; acc[3][3] += av.w*wv.w;
        }
        __syncthreads();
    }
    #pragma unroll
    for (int i = 0; i < 4; i++) {
        float4 v = make_float4(acc[i][0], acc[i][1], acc[i][2], acc[i][3]);
        *(float4*)(gpart + ((size_t)(ks * BB) + ty * 4 + i) * NG + nc * 64 + tx * 4) = v;
    }
}

// ---------------------------------------------------------------------------
// Cell: sum 8 K-partials (fixed order) + biases, LSTM update. Writes h both
// b-major (for kg1) and transposed hT[k][b] (for klog).
// ---------------------------------------------------------------------------
__global__ __launch_bounds__(256) void kc(
    int step, const float* __restrict__ gpart, const float* __restrict__ b_ih,
    const float* __restrict__ b_hh, float* __restrict__ cbuf,
    float* __restrict__ h_out, float* __restrict__ hT)
{
    int idx = blockIdx.x * 256 + threadIdx.x;   // < 64*768
    int b = idx / HID, j = idx % HID;
    float g4[4];
    #pragma unroll
    for (int g = 0; g < 4; g++) {
        int col = g * HID + j;
        float s = b_ih[col] + b_hh[col];
        #pragma unroll
        for (int ksd = 0; ksd < KSPLIT; ksd++)
            s += gpart[((size_t)ksd * BB + b) * NG + col];
        g4[g] = s;
    }
    float cprev = (step == 0) ? 0.f : cbuf[idx];
    float ig = 1.f / (1.f + expf(-g4[0]));
    float fg = 1.f / (1.f + expf(-g4[1]));
    float gg = tanhf(g4[2]);
    float og = 1.f / (1.f + expf(-g4[3]));
    float cn = fg * cprev + ig * gg;
    float hn = og * tanhf(cn);
    cbuf[idx] = cn;
    h_out[idx] = hn;
    hT[j * 64 + b] = hn;
}

// ---------------------------------------------------------------------------
// Logits GEMM + fused argmax — round-0 structure with 8 K-teams (1024 thr).
//
// 235 blocks x 1024 threads = 16 waves/block, 1 block/CU -> 4 waves/SIMD
// (2x the TLP of the 512-thread version; that one measured VALUBusy 25.4%
// = latency-bound at 2 waves/SIMD). Per-team code is VERBATIM the proven
// 82us kernel: t128 mapping, acc[8][8] split {ty*4, 32+ty*4} x {tx*4,
// 64+tx*4}, pa/pb register prefetch one chunk ahead, 4 conflict-free
// ds_read_b128 per 64 FMAs. Only deltas: 8 teams x K=96 (was 4 x 192) and
// chunk depth 16 (was 32), halving per-team LDS so 8 teams fit the same
// 100 KiB SMEM. Plain __launch_bounds__(1024) — NO min-waves hint (the
// (256,4) hint in an earlier round made the compiler alloc 64 VGPR and
// spill 1.8 GB/dispatch to scratch).
// Epilogue: sequential 8-team combine into L overlay + fused argmax.
// ---------------------------------------------------------------------------
__global__ __launch_bounds__(1024) void klog(
    const float* __restrict__ hT, const float* __restrict__ outW,
    const float* __restrict__ outb, float* __restrict__ pval, int* __restrict__ pidx)
{
    // Per team: As[16][68] (1088 f) + Bs[16][132] (2112 f) = 3200 f.
    // 8 teams = 25600 f = 100 KiB. Epilogue overlays L[64*128] (8192 f).
    __shared__ float SMEM[25600];
    __shared__ float fvv[1024];
    __shared__ int   fii[1024];

    const int tid  = threadIdx.x;
    const int team = tid >> 7;          // 0..7 : K-range [team*96, +96)
    const int t128 = tid & 127;
    const int ty = t128 >> 4;           // 0..7
    const int tx = t128 & 15;           // 0..15
    const int cb = blockIdx.x;
    const int c0 = cb * 128;
    const int tk0 = team * 96;

    float* Ast = SMEM + team * 3200;        // [k][m] stride 68
    float* Bst = Ast + 1088;                // [k][n] stride 132

    const int gc = (c0 + t128 < VOCAB) ? (c0 + t128) : (VOCAB - 1);
    const float* wrow = outW + (size_t)gc * HID + tk0;
    const float* arow = hT + ((size_t)tk0 + ty) * 64 + tx * 4;

    float4 pa[2], pb[4];
    #pragma unroll
    for (int q = 0; q < 2; q++) pa[q] = *(const float4*)(arow + (size_t)(q * 8) * 64);
    #pragma unroll
    for (int kq = 0; kq < 4; kq++) pb[kq] = *(const float4*)(wrow + kq * 4);

    float acc[8][8];
    #pragma unroll
    for (int i = 0; i < 8; i++)
        #pragma unroll
        for (int j = 0; j < 8; j++) acc[i][j] = 0.f;

    for (int ch = 0; ch < 6; ch++) {
        __syncthreads();   // previous chunk's readers done
        #pragma unroll
        for (int q = 0; q < 2; q++)
            *(float4*)(Ast + (ty + 8 * q) * 68 + tx * 4) = pa[q];
        #pragma unroll
        for (int kq = 0; kq < 4; kq++) {
            Bst[(kq * 4 + 0) * 132 + t128] = pb[kq].x;
            Bst[(kq * 4 + 1) * 132 + t128] = pb[kq].y;
            Bst[(kq * 4 + 2) * 132 + t128] = pb[kq].z;
            Bst[(kq * 4 + 3) * 132 + t128] = pb[kq].w;
        }
        __syncthreads();   // LDS ready
        if (ch < 5) {
            const int off = (ch + 1) * 16;
            #pragma unroll
            for (int q = 0; q < 2; q++)
                pa[q] = *(const float4*)(arow + (size_t)(off + q * 8) * 64);
            #pragma unroll
            for (int kq = 0; kq < 4; kq++)
                pb[kq] = *(const float4*)(wrow + off + kq * 4);
        }
        #pragma unroll 4
        for (int kk = 0; kk < 16; kk++) {
            const float* Ar = Ast + kk * 68;
            const float* Br = Bst + kk * 132;
            float4 a0 = *(const float4*)(Ar + ty * 4);         // broadcast
            float4 a1 = *(const float4*)(Ar + 32 + ty * 4);    // broadcast
            float4 b0 = *(const float4*)(Br + tx * 4);         // 2-way (free)
            float4 b1 = *(const float4*)(Br + 64 + tx * 4);    // 2-way (free)
            float av[8] = {a0.x,a0.y,a0.z,a0.w,a1.x,a1.y,a1.z,a1.w};
            float bv[8] = {b0.x,b0.y,b0.z,b0.w,b1.x,b1.y,b1.z,b1.w};
            #pragma unroll
            for (int i = 0; i < 8; i++)
                #pragma unroll
                for (int j = 0; j < 8; j++)
                    acc[i][j] = fmaf(av[i], bv[j], acc[i][j]);
        }
    }

    // ---- epilogue: sequential team combine (deterministic) ----
    float* L = SMEM;   // 64 x 128
    __syncthreads();
    for (int tm = 0; tm < 8; tm++) {
        if (team == tm) {
            #pragma unroll
            for (int i = 0; i < 8; i++) {
                const int m = (i < 4) ? (ty * 4 + i) : (32 + ty * 4 + i - 4);
                #pragma unroll
                for (int j = 0; j < 8; j++) {
                    const int n = (j < 4) ? (tx * 4 + j) : (64 + tx * 4 + j - 4);
                    if (tm == 0) L[m * 128 + n] = acc[i][j];
                    else         L[m * 128 + n] += acc[i][j];
                }
            }
        }
        __syncthreads();
    }

    {   // bias + argmax: thread: batch row b = tid>>4, segment seg = tid&15
        const int b = tid >> 4, seg = tid & 15;
        float bvv = -FLT_MAX; int bii = INT_MAX;
        #pragma unroll 4
        for (int cc = 0; cc < 8; cc++) {
            int col = seg * 8 + cc;
            int c = c0 + col;
            if (c < VOCAB) {
                float v = L[b * 128 + col] + outb[c];
                if (v > bvv) { bvv = v; bii = c; }   // ascending -> first occurrence
            }
        }
        fvv[tid] = bvv; fii[tid] = bii;
    }
    __syncthreads();
    if (tid < BB) {
        float bvv = -FLT_MAX; int bii = INT_MAX;
        #pragma unroll
        for (int s = 0; s < 16; s++) {
            float v = fvv[tid * 16 + s]; int ix = fii[tid * 16 + s];
            if (v > bvv || (v == bvv && ix < bii)) { bvv = v; bii = ix; }
        }
        pval[tid * NBL + cb] = bvv;
        pidx[tid * NBL + cb] = bii;
    }
}

// ---------------------------------------------------------------------------
// Finalize token for batch row b.
// ---------------------------------------------------------------------------
__global__ __launch_bounds__(256) void kfin(
    int step, const float* __restrict__ pval, const int* __restrict__ pidx,
    int* __restrict__ tok_ws, float* __restrict__ gen)
{
    const int b = blockIdx.x, tid = threadIdx.x;
    __shared__ float sv[256];
    __shared__ int   si[256];
    float bv = -FLT_MAX; int bi = INT_MAX;
    for (int p = tid; p < NBL; p += 256) {
        float v = pval[b * NBL + p]; int ix = pidx[b * NBL + p];
        if (v > bv || (v == bv && ix < bi)) { bv = v; bi = ix; }
    }
    sv[tid] = bv; si[tid] = bi;
    __syncthreads();
    for (int st = 128; st; st >>= 1) {
        if (tid < st) {
            float v = sv[tid + st]; int ix = si[tid + st];
            if (v > sv[tid] || (v == sv[tid] && ix < si[tid])) { sv[tid] = v; si[tid] = ix; }
        }
        __syncthreads();
    }
    if (tid == 0) {
        tok_ws[b] = si[0];
        gen[b * TSTEPS + step] = (float)si[0];
    }
}

// ---------------------------------------------------------------------------
extern "C" void kernel_launch(void* const* d_in, const int* in_sizes, int n_in,
                              void* d_out, int out_size, void* d_ws, size_t ws_size,
                              hipStream_t stream)
{
    const float* feat = (const float*)d_in[0];
    const float* emb  = (const float*)d_in[1];
    const float* W_ih = (const float*)d_in[2];
    const float* W_hh = (const float*)d_in[3];
    const float* b_ih = (const float*)d_in[4];
    const float* b_hh = (const float*)d_in[5];
    const float* outW = (const float*)d_in[6];
    const float* outb = (const float*)d_in[7];
    const float* c1W  = (const float*)d_in[8];
    const float* c1b  = (const float*)d_in[9];
    const float* c2W  = (const float*)d_in[10];
    const float* c2b  = (const float*)d_in[11];
    (void)in_sizes; (void)n_in; (void)out_size; (void)ws_size;

    float* out = (float*)d_out;
    float* gen = out + BB * 2;                  // generated (64x32), as floats

    float* ws     = (float*)d_ws;
    float* hbuf   = ws;                               // 64*768  (b-major h)
    float* cbuf   = hbuf + BB * HID;                  // 64*768
    float* hT     = cbuf + BB * HID;                  // 768*64  (k-major h)
    float* gpart  = hT + HID * 64;                    // 8*64*3072
    float* pval   = gpart + (size_t)KSPLIT * BB * NG; // 64*235
    int*   pidx   = (int*)(pval + BB * NBL);          // 64*235
    int*   tok    = pidx + BB * NBL;                  // 64
    float* hid_ws = (float*)(tok + BB);               // 64*512

    kc1<<<dim3(4, BB), 256, 0, stream>>>(feat, c1W, c1b, hid_ws);
    kc2<<<BB, 256, 0, stream>>>(hid_ws, c2W, c2b, out);
    kprep<<<dim3(HID * 64 / 256), 256, 0, stream>>>(feat, hT);

    for (int t = 0; t < TSTEPS; t++) {
        const float* h_in = (t == 0) ? feat : hbuf;
        kg1<<<dim3(48, KSPLIT), 256, 0, stream>>>(t, tok, emb, W_ih, W_hh, h_in, gpart);
        kc<<<dim3(192), 256, 0, stream>>>(t, gpart, b_ih, b_hh, cbuf, hbuf, hT);
        klog<<<dim3(NBL), 1024, 0, stream>>>(hT, outW, outb, pval, pidx);
        kfin<<<BB, 256, 0, stream>>>(t, pval, pidx, tok, gen);
    }
}